// Round 18
// baseline (147.557 us; speedup 1.0000x reference)
//
#include <hip/hip_runtime.h>
#include <hip/hip_bf16.h>

// ---------------------------------------------------------------------------
// GCN layer: out = D^{-1/2} (A_set + I) D^{-1/2} @ (x @ W) + bias
// Pipeline (4 dispatches) — r18: spmm explicit depth-8 prefetch.
//   prep:   [memset mask | cast x->bf16 | transpose W | pads]
//   front2: [gemm 64x128 (blocks 0-511) | edge atomicOr (512-1535)]
//           (r16 win: latency-bound atomics hide under compute-bound GEMM)
//   ell:    LDS-buffered ELL build + ONE coalesced 256B row store (r17 win)
//   spmm:   r9 core (quarter-D XCD-pinned, sdinv LDS table, 1024-thr)
//     + EXPLICIT DEPTH-8 PREFETCH. Arithmetic: VALU floor 17.6us, L2 16us,
//     measured ~36-40 -> per-iter ~40cyc = serial ds_read->L2-load chain
//     (~320cyc) / 8 waves. pf[8]/dj[8] statically indexed give 64 in-flight
//     chains/SIMD -> chain cost ~5cyc/iter, VALU-bound ~22-25us. r7's null
//     prefetch was on the FULL-D shape = L3-BW-bound regime where MLP can't
//     pay (rule #23); quarter-D is L2-resident latency-bound = right regime.
//   Ledger: r17 = 144.77 best. fill ~46 in window; atomics T<=20; 10 spmm
//   shapes floor ~36.
// ---------------------------------------------------------------------------

#define ELL_STRIDE 128

typedef __attribute__((ext_vector_type(8))) short bf16x8;
typedef __attribute__((ext_vector_type(4))) float f32x4;
typedef __attribute__((ext_vector_type(2))) float f32x2;

__device__ __forceinline__ unsigned short f2bf(float f) {
  unsigned u = __float_as_uint(f);
  u = (u + 0x7fff + ((u >> 16) & 1)) >> 16;  // RNE
  return (unsigned short)u;
}
__device__ __forceinline__ float bflo(unsigned u) {
  return __uint_as_float(u << 16);
}
__device__ __forceinline__ float bfhi(unsigned u) {
  return __uint_as_float(u & 0xffff0000u);
}

// ---- prep: [0,mb): memset mask  [mb,+cb): cast  [..+tb): transpose
//            [last]: Hs pad row + dinv[M]
__global__ __launch_bounds__(256) void prep_kernel(
    unsigned* __restrict__ mask, int mask_words_total,
    const float* __restrict__ x, unsigned short* __restrict__ xb, int n4,
    const float* __restrict__ W, unsigned short* __restrict__ Wt, int K, int N,
    unsigned short* __restrict__ Hs, float* __restrict__ dinv, int n_nodes,
    int mset_blocks, int cast_blocks, int tr_blocks) {
  const int bid = blockIdx.x;
  if (bid < mset_blocks) {
    // 8MB zero: 512 blocks x 256 thr x 4 x uint4
    uint4* m4 = (uint4*)mask;
    const int n16 = mask_words_total >> 2;
    const uint4 z = make_uint4(0u, 0u, 0u, 0u);
#pragma unroll
    for (int r = 0; r < 4; ++r) {
      const int t = (bid * 4 + r) * 256 + threadIdx.x;
      if (t < n16) m4[t] = z;
    }
    return;
  }
  if (bid < mset_blocks + cast_blocks) {
    const int t = (bid - mset_blocks) * 256 + threadIdx.x;
    if (t < n4) {
      float4 v = ((const float4*)x)[t];
      ushort4 o;
      o.x = f2bf(v.x); o.y = f2bf(v.y); o.z = f2bf(v.z); o.w = f2bf(v.w);
      ((ushort4*)xb)[t] = o;
    }
    return;
  }
  if (bid < mset_blocks + cast_blocks + tr_blocks) {
    // transpose+cast: W[K][N] fp32 -> Wt[N][K] bf16, 32x32 tiles
    __shared__ float tile[32][33];
    const int b = bid - mset_blocks - cast_blocks;
    const int bx = b & ((N >> 5) - 1);
    const int by = b >> (31 - __builtin_clz(N >> 5));
    const int tx = threadIdx.x & 31;
    const int ty = threadIdx.x >> 5;  // 0..7
#pragma unroll
    for (int r = 0; r < 4; ++r)
      tile[ty + 8 * r][tx] = W[(size_t)(by * 32 + ty + 8 * r) * N + bx * 32 + tx];
    __syncthreads();
#pragma unroll
    for (int r = 0; r < 4; ++r)
      Wt[(size_t)(bx * 32 + ty + 8 * r) * K + by * 32 + tx] =
          f2bf(tile[tx][ty + 8 * r]);
    return;
  }
  // zero the ELL pad row Hs[n_nodes][:] and its scale dinv[n_nodes]
  {
    const int t = threadIdx.x;
    if (t < (N >> 1)) ((unsigned*)(Hs + (size_t)n_nodes * N))[t] = 0;
    if (t == 0) dinv[n_nodes] = 0.f;
  }
}

// ---- front2: [0,gb): gemm 64x128 (unscaled)   [gb..): edge atomics.
__global__ __launch_bounds__(256) void front2_kernel(
    const unsigned short* __restrict__ xb,  // [M][K] bf16
    const unsigned short* __restrict__ Wt,  // [N][K] bf16
    unsigned short* __restrict__ Hs,        // [M+1][N] bf16 (unscaled)
    const int* __restrict__ ei, unsigned* __restrict__ mask, int n_edges,
    int M, int N, int K, int words, int gemm_blocks, int nbx_sh) {
  // 64x128 tile, BK=64, 4 waves 2x2, wave tile 32x64 (acc[2][4] 16x16x32).
  // B staged with XOR source pre-swizzle (stride-128B fragment read spans
  // all 8 bank-quads; global_load_lds forces a linear LDS dest).
  __shared__ unsigned short As[512 * 8];
  __shared__ unsigned short Bs[1024 * 8];

  const int tid = threadIdx.x;
  const int bid = blockIdx.x;

  if (bid < gemm_blocks) {
    const int wave = tid >> 6;
    const int lane = tid & 63;
    const int q = lane >> 4;   // quad
    const int c = lane & 15;
    const int bx = bid & ((1 << nbx_sh) - 1);
    const int by = bid >> nbx_sh;
    const int m0 = by * 64;
    const int n0 = bx * 128;
    const int wr = wave >> 1, wc = wave & 1;

    f32x4 acc[2][4] = {};

    for (int k0 = 0; k0 < K; k0 += 64) {
#pragma unroll
      for (int t = 0; t < 2; ++t) {
        const int sbase = t * 256 + wave * 64;
        const int s = sbase + lane;
        const unsigned short* g =
            xb + (size_t)(m0 + (s & 63)) * K + k0 + (s >> 6) * 8;
        __builtin_amdgcn_global_load_lds(
            (const __attribute__((address_space(1))) void*)g,
            (__attribute__((address_space(3))) void*)(As + sbase * 8), 16, 0, 0);
      }
#pragma unroll
      for (int t = 0; t < 4; ++t) {
        const int sbase = t * 256 + wave * 64;
        const int s = sbase + lane;
        const int bn = s >> 3;
        const int bk = (s & 7) ^ (bn & 7);  // XOR-swizzled source (same 128B seg)
        const unsigned short* g =
            Wt + (size_t)(n0 + bn) * K + k0 + bk * 8;
        __builtin_amdgcn_global_load_lds(
            (const __attribute__((address_space(1))) void*)g,
            (__attribute__((address_space(3))) void*)(Bs + sbase * 8), 16, 0, 0);
      }
      __syncthreads();

#pragma unroll
      for (int kk = 0; kk < 2; ++kk) {
        bf16x8 a[2], b[4];
#pragma unroll
        for (int tm = 0; tm < 2; ++tm) {
          const int row = wr * 32 + tm * 16 + c;
          a[tm] = *(const bf16x8*)(As + (((kk * 4 + q) * 64) + row) * 8);
        }
#pragma unroll
        for (int tn = 0; tn < 4; ++tn) {
          const int n = wc * 64 + tn * 16 + c;
          b[tn] = *(const bf16x8*)(Bs + (n * 8 + ((kk * 4 + q) ^ (n & 7))) * 8);
        }
#pragma unroll
        for (int tm = 0; tm < 2; ++tm)
#pragma unroll
          for (int tn = 0; tn < 4; ++tn)
            acc[tm][tn] = __builtin_amdgcn_mfma_f32_16x16x32_bf16(
                a[tm], b[tn], acc[tm][tn], 0, 0, 0);
      }
      __syncthreads();
    }

    // C/D mapping: col=lane&15, row=quad*4+reg ; unscaled store
#pragma unroll
    for (int tm = 0; tm < 2; ++tm) {
#pragma unroll
      for (int r = 0; r < 4; ++r) {
        const int grow = m0 + wr * 32 + tm * 16 + q * 4 + r;
#pragma unroll
        for (int tn = 0; tn < 4; ++tn) {
          const int gcol = n0 + wc * 64 + tn * 16 + c;
          Hs[(size_t)grow * N + gcol] = f2bf(acc[tm][tn][r]);
        }
      }
    }
    return;
  }

  // ---- edge atomics: fire-and-forget (never read the return value)
  {
    const int e = (bid - gemm_blocks) * 256 + tid;
    if (e < n_edges) {
      const int u = ei[e];
      const int v = ei[e + n_edges];
      atomicOr(&mask[(size_t)u * words + (v >> 5)], 1u << (v & 31));
      atomicOr(&mask[(size_t)v * words + (u >> 5)], 1u << (u & 31));
    }
  }
}

// ---- ell: one wave per node. Build the 256B ELL row in LDS (scatter via
// ds_write_b16 = cheap), then ONE coalesced 64-lane x 4B global store.
__global__ __launch_bounds__(256) void ell_kernel(
    const unsigned* __restrict__ mask, unsigned short* __restrict__ ell,
    int* __restrict__ deg, float* __restrict__ dinv, int M, int words) {
  __shared__ unsigned short rowbuf[4][ELL_STRIDE];
  const int wave = threadIdx.x >> 6, lane = threadIdx.x & 63;
  const int node = blockIdx.x * 4 + wave;
  const unsigned* __restrict__ row = mask + (size_t)node * words;

  // load 4 words/lane (coalesced), count
  unsigned w[4];
  int cnt = 0;
#pragma unroll
  for (int j = 0; j < 4; ++j) {
    w[j] = row[lane + j * 64];
    cnt += __popc(w[j]);
  }
  // exclusive prefix over lanes
  int x = cnt;
#pragma unroll
  for (int d = 1; d < 64; d <<= 1) {
    int y = __shfl_up(x, d, 64);
    if (lane >= d) x += y;
  }
  int pos = x - cnt;
  const int total = __shfl(x, 63, 64);  // row popcount

  // emit to LDS rowbuf (scatter, cheap)
#pragma unroll
  for (int j = 0; j < 4; ++j) {
    unsigned bits = w[j];
    const int wj = lane + j * 64;
    while (bits) {
      const int b = __builtin_ctz(bits);
      bits &= bits - 1;
      if (pos < ELL_STRIDE) rowbuf[wave][pos] = (unsigned short)((wj << 5) + b);
      ++pos;
    }
  }
  // self entry at [total], pads (index M -> dinv 0, zero row) after
  for (int p = total + lane; p < ELL_STRIDE; p += 64)
    rowbuf[wave][p] = (unsigned short)(p == total ? node : M);

  // coalesced row write: 64 lanes x 4B = 256B
  ((unsigned*)(ell + (size_t)node * ELL_STRIDE))[lane] =
      ((const unsigned*)rowbuf[wave])[lane];

  if (lane == 0) {
    const int dd = total + 1;  // + self
    deg[node] = dd < ELL_STRIDE ? dd : ELL_STRIDE;
    dinv[node] = rsqrtf((float)total + 1.0f);
  }
}

// ---- spmm: grid 4*(n/16) x 1024 thr; wave = one node-quarter.
// qt = bid&3 (bid%8 XCD round-robin -> quarter k on XCDs {k,k+4}, 2.1MB
// L2-resident). Block stages dinv[8193] (32KB) into LDS once; ji =
// (byte offset, dinv_j) from scattered LDS reads, PADDED to 136 entries
// (pad -> zeroed Hs row, dinv 0) so the pipeline overruns safely.
// EXPLICIT DEPTH-8 PREFETCH (pf[8]/dj[8], statically indexed): 8 loads in
// flight per wave x 8 waves/SIMD = 64 chains -> serial ds_read->L2-load
// chain (~320cyc) amortized to ~5cyc/iter; VALU floor ~20cyc/iter remains.
// LDS 32.8 + 17.4 = 50.2KB -> 2 blocks/CU (32 waves, full occupancy).
__global__ __launch_bounds__(1024) void spmm_kernel(
    const unsigned short* __restrict__ ell, const int* __restrict__ deg,
    const float* __restrict__ dinv, const unsigned short* __restrict__ Hs,
    const float* __restrict__ bias, float* __restrict__ out, int n, int D) {
  __shared__ float sdinv[8193];
  __shared__ uint2 ji[16][ELL_STRIDE + 8];
  const int tid = threadIdx.x;
  const int wave = tid >> 6, lane = tid & 63;
  const int bid = blockIdx.x;
  const int qt = bid & 3;                     // quarter, XCD-pinned
  const int i = (bid >> 2) * 16 + wave;       // node (n divisible by 16)
  const unsigned rowbytes = (unsigned)(D * 2);

  for (int t = tid; t < n + 1; t += 1024) sdinv[t] = dinv[t];
  __syncthreads();

  {  // stage (byte offset, dinv[j]) — scattered LDS lookups, cheap
    const unsigned j0 = ell[(size_t)i * ELL_STRIDE + lane];
    const unsigned j1 = ell[(size_t)i * ELL_STRIDE + 64 + lane];
    ji[wave][lane] = make_uint2(j0 * rowbytes, __float_as_uint(sdinv[j0]));
    ji[wave][64 + lane] = make_uint2(j1 * rowbytes, __float_as_uint(sdinv[j1]));
    if (lane < 8)  // overrun pad: zero row, weight 0
      ji[wave][ELL_STRIDE + lane] = make_uint2((unsigned)n * rowbytes, 0u);
  }
  const int d = deg[i];            // includes the self entry
  const float di = sdinv[i];
  const int kmax = (d + 7) & ~7;   // ELL pads (dinv 0, zero row) cover tail

  // this wave reads bytes [qt*256, qt*256+256) of each row: 4B per lane
  const char* __restrict__ hb = (const char*)Hs + qt * 256 + lane * 4;
  float a0 = 0.f, a1 = 0.f;

  // depth-8 software pipeline (statically indexed, rule-#20-safe)
  unsigned pf[8], dj[8];
#pragma unroll
  for (int p = 0; p < 8; ++p) {
    const uint2 e = ji[wave][p];
    dj[p] = e.y;
    pf[p] = *(const unsigned*)(hb + e.x);
  }
  for (int k = 0; k < kmax; k += 8) {
#pragma unroll
    for (int p = 0; p < 8; ++p) {
      const float djv = __uint_as_float(dj[p]);
      const unsigned hv = pf[p];
      a0 += djv * bflo(hv);
      a1 += djv * bfhi(hv);
      const uint2 e = ji[wave][k + 8 + p];  // max kmax+7 <= 135 < 136
      dj[p] = e.y;
      pf[p] = *(const unsigned*)(hb + e.x);
    }
  }

  const int col = qt * (D >> 2) + lane * 2;
  const float2 b = *(const float2*)(bias + col);
  f32x2 o;
  o.x = di * a0 + b.x;
  o.y = di * a1 + b.y;
  __builtin_nontemporal_store(o, (f32x2*)(out + (size_t)i * D + col));
}

extern "C" void kernel_launch(void* const* d_in, const int* in_sizes, int n_in,
                              void* d_out, int out_size, void* d_ws, size_t ws_size,
                              hipStream_t stream) {
  const float* x    = (const float*)d_in[0];
  const int*   ei   = (const int*)d_in[1];
  const float* W    = (const float*)d_in[2];
  const float* bias = (const float*)d_in[3];
  float* out = (float*)d_out;

  const int d_out_dim = in_sizes[3];             // 512
  const int d_in_dim  = in_sizes[2] / d_out_dim; // 512
  const int n_nodes   = in_sizes[0] / d_in_dim;  // 8192
  const int n_edges   = in_sizes[1] / 2;         // 262144
  const int words     = (n_nodes + 31) / 32;     // 256

  // workspace layout (bytes)
  char* ws = (char*)d_ws;
  size_t off = 0;
  unsigned* mask = (unsigned*)(ws + off); off += (size_t)n_nodes * words * 4;       // 8 MB
  int* deg       = (int*)(ws + off);      off += (size_t)n_nodes * 4;               // 32 KB
  float* dinv    = (float*)(ws + off);    off += (size_t)(n_nodes + 1) * 4;         // 32 KB + pad
  unsigned short* ell = (unsigned short*)(ws + off); off += (size_t)n_nodes * ELL_STRIDE * 2; // 2 MB
  unsigned short* xb  = (unsigned short*)(ws + off); off += (size_t)n_nodes * d_in_dim * 2;   // 8 MB
  unsigned short* Wt  = (unsigned short*)(ws + off); off += (size_t)d_in_dim * d_out_dim * 2; // 512 KB
  unsigned short* Hs  = (unsigned short*)(ws + off);
  off += (size_t)(n_nodes + 1) * d_out_dim * 2;  // 8 MB + pad row

  // 1) prep: memset mask | cast | transpose | pads
  const int mask_words_total = n_nodes * words;               // 2M words
  const int mset_blocks = (mask_words_total / 4 + 1023) / 1024;  // 512
  const int n4 = n_nodes * d_in_dim / 4;
  const int cast_blocks = (n4 + 255) / 256;                   // 4096
  const int tr_blocks = (d_in_dim / 32) * (d_out_dim / 32);   // 256
  prep_kernel<<<mset_blocks + cast_blocks + tr_blocks + 1, 256, 0, stream>>>(
      mask, mask_words_total, x, xb, n4, W, Wt, d_in_dim, d_out_dim,
      Hs, dinv, n_nodes, mset_blocks, cast_blocks, tr_blocks);

  // 2) front2: gemm (launches first, fills CUs) | edge atomics (hide under)
  const int nbx = d_out_dim / 128;                            // 4
  const int nbx_sh = 31 - __builtin_clz(nbx);                 // 2
  const int gemm_blocks = nbx * (n_nodes / 64);               // 512
  const int edge_blocks = (n_edges + 255) / 256;              // 1024
  front2_kernel<<<gemm_blocks + edge_blocks, 256, 0, stream>>>(
      xb, Wt, Hs, ei, mask, n_edges,
      n_nodes, d_out_dim, d_in_dim, words, gemm_blocks, nbx_sh);

  // 3) ell: LDS-buffered build + coalesced row store, deg + dinv
  ell_kernel<<<n_nodes / 4, 256, 0, stream>>>(mask, ell, deg, dinv,
                                              n_nodes, words);

  // 4) spmm: quarter-D XCD-pinned + sdinv LDS + depth-8 prefetch
  const int spmm_blocks = 4 * (n_nodes / 16);                 // 2048
  spmm_kernel<<<spmm_blocks, 1024, 0, stream>>>(ell, deg, dinv, Hs, bias, out,
                                                n_nodes, d_out_dim);
}

// Round 19
// 144.150 us; speedup vs baseline: 1.0236x; 1.0236x over previous
//
#include <hip/hip_runtime.h>
#include <hip/hip_bf16.h>

// ---------------------------------------------------------------------------
// GCN layer: out = D^{-1/2} (A_set + I) D^{-1/2} @ (x @ W) + bias
// FINAL (r17 configuration, harness-verified best 144.77us).
// Pipeline (4 dispatches):
//   prep:   [memset mask | cast x->bf16 | transpose W | pads]
//   front2: [gemm 64x128 (blocks 0-511) | edge atomicOr (512-1535)]
//           (r16 win: latency-bound atomics hide under compute-bound GEMM;
//            r10 probe: single atomic pass T<=20us)
//   ell:    LDS-buffered ELL build + ONE coalesced 256B row store (r17 win;
//           r16's scattered 2B global stores defeated write-combining)
//   spmm:   quarter-D XCD-pinned (qt=bid&3, 2.1MB/XCD L2-resident, FETCH
//           17MB), sdinv LDS table (32KB staged once/block), 1024-thr,
//           uint2 ji, ~66-iter loop.
// Closed theory ledger (18 rounds):
//   - spmm: 11 shapes all in 36-48us band; L2-residency proven (FETCH 80->17MB)
//     with no time delta; explicit MLP depth-8 null in BW-regime (r7) AND
//     in latency-regime (r18, +2.8) -> dependent-chain floor ~36us structural.
//   - adjacency: LDS-bitmask rewrite 95us (r7, rejected); atomics T<=20
//     (r10 idempotent-x2 probe) and fully hidden under gemm (r16).
//   - gemm: 64x128 @ 2 blocks/CU beats 128x128 @ 1/CU; XOR-swizzled B.
//   - harness re-poison fill ~46us sits inside the timed window (floor).
//   Budget: 46+7+~22+7+36+launch ~= 145 == measured.
// ---------------------------------------------------------------------------

#define ELL_STRIDE 128

typedef __attribute__((ext_vector_type(8))) short bf16x8;
typedef __attribute__((ext_vector_type(4))) float f32x4;
typedef __attribute__((ext_vector_type(2))) float f32x2;

__device__ __forceinline__ unsigned short f2bf(float f) {
  unsigned u = __float_as_uint(f);
  u = (u + 0x7fff + ((u >> 16) & 1)) >> 16;  // RNE
  return (unsigned short)u;
}
__device__ __forceinline__ float bflo(unsigned u) {
  return __uint_as_float(u << 16);
}
__device__ __forceinline__ float bfhi(unsigned u) {
  return __uint_as_float(u & 0xffff0000u);
}

// ---- prep: [0,mb): memset mask  [mb,+cb): cast  [..+tb): transpose
//            [last]: Hs pad row + dinv[M]
__global__ __launch_bounds__(256) void prep_kernel(
    unsigned* __restrict__ mask, int mask_words_total,
    const float* __restrict__ x, unsigned short* __restrict__ xb, int n4,
    const float* __restrict__ W, unsigned short* __restrict__ Wt, int K, int N,
    unsigned short* __restrict__ Hs, float* __restrict__ dinv, int n_nodes,
    int mset_blocks, int cast_blocks, int tr_blocks) {
  const int bid = blockIdx.x;
  if (bid < mset_blocks) {
    // 8MB zero: 512 blocks x 256 thr x 4 x uint4
    uint4* m4 = (uint4*)mask;
    const int n16 = mask_words_total >> 2;
    const uint4 z = make_uint4(0u, 0u, 0u, 0u);
#pragma unroll
    for (int r = 0; r < 4; ++r) {
      const int t = (bid * 4 + r) * 256 + threadIdx.x;
      if (t < n16) m4[t] = z;
    }
    return;
  }
  if (bid < mset_blocks + cast_blocks) {
    const int t = (bid - mset_blocks) * 256 + threadIdx.x;
    if (t < n4) {
      float4 v = ((const float4*)x)[t];
      ushort4 o;
      o.x = f2bf(v.x); o.y = f2bf(v.y); o.z = f2bf(v.z); o.w = f2bf(v.w);
      ((ushort4*)xb)[t] = o;
    }
    return;
  }
  if (bid < mset_blocks + cast_blocks + tr_blocks) {
    // transpose+cast: W[K][N] fp32 -> Wt[N][K] bf16, 32x32 tiles
    __shared__ float tile[32][33];
    const int b = bid - mset_blocks - cast_blocks;
    const int bx = b & ((N >> 5) - 1);
    const int by = b >> (31 - __builtin_clz(N >> 5));
    const int tx = threadIdx.x & 31;
    const int ty = threadIdx.x >> 5;  // 0..7
#pragma unroll
    for (int r = 0; r < 4; ++r)
      tile[ty + 8 * r][tx] = W[(size_t)(by * 32 + ty + 8 * r) * N + bx * 32 + tx];
    __syncthreads();
#pragma unroll
    for (int r = 0; r < 4; ++r)
      Wt[(size_t)(bx * 32 + ty + 8 * r) * K + by * 32 + tx] =
          f2bf(tile[tx][ty + 8 * r]);
    return;
  }
  // zero the ELL pad row Hs[n_nodes][:] and its scale dinv[n_nodes]
  {
    const int t = threadIdx.x;
    if (t < (N >> 1)) ((unsigned*)(Hs + (size_t)n_nodes * N))[t] = 0;
    if (t == 0) dinv[n_nodes] = 0.f;
  }
}

// ---- front2: [0,gb): gemm 64x128 (unscaled)   [gb..): edge atomics.
__global__ __launch_bounds__(256) void front2_kernel(
    const unsigned short* __restrict__ xb,  // [M][K] bf16
    const unsigned short* __restrict__ Wt,  // [N][K] bf16
    unsigned short* __restrict__ Hs,        // [M+1][N] bf16 (unscaled)
    const int* __restrict__ ei, unsigned* __restrict__ mask, int n_edges,
    int M, int N, int K, int words, int gemm_blocks, int nbx_sh) {
  // 64x128 tile, BK=64, 4 waves 2x2, wave tile 32x64 (acc[2][4] 16x16x32).
  // B staged with XOR source pre-swizzle (stride-128B fragment read spans
  // all 8 bank-quads; global_load_lds forces a linear LDS dest).
  __shared__ unsigned short As[512 * 8];
  __shared__ unsigned short Bs[1024 * 8];

  const int tid = threadIdx.x;
  const int bid = blockIdx.x;

  if (bid < gemm_blocks) {
    const int wave = tid >> 6;
    const int lane = tid & 63;
    const int q = lane >> 4;   // quad
    const int c = lane & 15;
    const int bx = bid & ((1 << nbx_sh) - 1);
    const int by = bid >> nbx_sh;
    const int m0 = by * 64;
    const int n0 = bx * 128;
    const int wr = wave >> 1, wc = wave & 1;

    f32x4 acc[2][4] = {};

    for (int k0 = 0; k0 < K; k0 += 64) {
#pragma unroll
      for (int t = 0; t < 2; ++t) {
        const int sbase = t * 256 + wave * 64;
        const int s = sbase + lane;
        const unsigned short* g =
            xb + (size_t)(m0 + (s & 63)) * K + k0 + (s >> 6) * 8;
        __builtin_amdgcn_global_load_lds(
            (const __attribute__((address_space(1))) void*)g,
            (__attribute__((address_space(3))) void*)(As + sbase * 8), 16, 0, 0);
      }
#pragma unroll
      for (int t = 0; t < 4; ++t) {
        const int sbase = t * 256 + wave * 64;
        const int s = sbase + lane;
        const int bn = s >> 3;
        const int bk = (s & 7) ^ (bn & 7);  // XOR-swizzled source (same 128B seg)
        const unsigned short* g =
            Wt + (size_t)(n0 + bn) * K + k0 + bk * 8;
        __builtin_amdgcn_global_load_lds(
            (const __attribute__((address_space(1))) void*)g,
            (__attribute__((address_space(3))) void*)(Bs + sbase * 8), 16, 0, 0);
      }
      __syncthreads();

#pragma unroll
      for (int kk = 0; kk < 2; ++kk) {
        bf16x8 a[2], b[4];
#pragma unroll
        for (int tm = 0; tm < 2; ++tm) {
          const int row = wr * 32 + tm * 16 + c;
          a[tm] = *(const bf16x8*)(As + (((kk * 4 + q) * 64) + row) * 8);
        }
#pragma unroll
        for (int tn = 0; tn < 4; ++tn) {
          const int n = wc * 64 + tn * 16 + c;
          b[tn] = *(const bf16x8*)(Bs + (n * 8 + ((kk * 4 + q) ^ (n & 7))) * 8);
        }
#pragma unroll
        for (int tm = 0; tm < 2; ++tm)
#pragma unroll
          for (int tn = 0; tn < 4; ++tn)
            acc[tm][tn] = __builtin_amdgcn_mfma_f32_16x16x32_bf16(
                a[tm], b[tn], acc[tm][tn], 0, 0, 0);
      }
      __syncthreads();
    }

    // C/D mapping: col=lane&15, row=quad*4+reg ; unscaled store
#pragma unroll
    for (int tm = 0; tm < 2; ++tm) {
#pragma unroll
      for (int r = 0; r < 4; ++r) {
        const int grow = m0 + wr * 32 + tm * 16 + q * 4 + r;
#pragma unroll
        for (int tn = 0; tn < 4; ++tn) {
          const int gcol = n0 + wc * 64 + tn * 16 + c;
          Hs[(size_t)grow * N + gcol] = f2bf(acc[tm][tn][r]);
        }
      }
    }
    return;
  }

  // ---- edge atomics: fire-and-forget (never read the return value)
  {
    const int e = (bid - gemm_blocks) * 256 + tid;
    if (e < n_edges) {
      const int u = ei[e];
      const int v = ei[e + n_edges];
      atomicOr(&mask[(size_t)u * words + (v >> 5)], 1u << (v & 31));
      atomicOr(&mask[(size_t)v * words + (u >> 5)], 1u << (u & 31));
    }
  }
}

// ---- ell: one wave per node. Build the 256B ELL row in LDS (scatter via
// ds_write_b16 = cheap), then ONE coalesced 64-lane x 4B global store.
__global__ __launch_bounds__(256) void ell_kernel(
    const unsigned* __restrict__ mask, unsigned short* __restrict__ ell,
    int* __restrict__ deg, float* __restrict__ dinv, int M, int words) {
  __shared__ unsigned short rowbuf[4][ELL_STRIDE];
  const int wave = threadIdx.x >> 6, lane = threadIdx.x & 63;
  const int node = blockIdx.x * 4 + wave;
  const unsigned* __restrict__ row = mask + (size_t)node * words;

  // load 4 words/lane (coalesced), count
  unsigned w[4];
  int cnt = 0;
#pragma unroll
  for (int j = 0; j < 4; ++j) {
    w[j] = row[lane + j * 64];
    cnt += __popc(w[j]);
  }
  // exclusive prefix over lanes
  int x = cnt;
#pragma unroll
  for (int d = 1; d < 64; d <<= 1) {
    int y = __shfl_up(x, d, 64);
    if (lane >= d) x += y;
  }
  int pos = x - cnt;
  const int total = __shfl(x, 63, 64);  // row popcount

  // emit to LDS rowbuf (scatter, cheap)
#pragma unroll
  for (int j = 0; j < 4; ++j) {
    unsigned bits = w[j];
    const int wj = lane + j * 64;
    while (bits) {
      const int b = __builtin_ctz(bits);
      bits &= bits - 1;
      if (pos < ELL_STRIDE) rowbuf[wave][pos] = (unsigned short)((wj << 5) + b);
      ++pos;
    }
  }
  // self entry at [total], pads (index M -> dinv 0, zero row) after
  for (int p = total + lane; p < ELL_STRIDE; p += 64)
    rowbuf[wave][p] = (unsigned short)(p == total ? node : M);

  // coalesced row write: 64 lanes x 4B = 256B
  ((unsigned*)(ell + (size_t)node * ELL_STRIDE))[lane] =
      ((const unsigned*)rowbuf[wave])[lane];

  if (lane == 0) {
    const int dd = total + 1;  // + self
    deg[node] = dd < ELL_STRIDE ? dd : ELL_STRIDE;
    dinv[node] = rsqrtf((float)total + 1.0f);
  }
}

// ---- spmm: grid 4*(n/16) x 1024 thr; wave = one node-quarter.
// qt = bid&3 (bid%8 XCD round-robin -> quarter k on XCDs {k,k+4}, 2.1MB
// L2-resident). Block stages dinv[8193] (32KB) into LDS once, coalesced;
// ji = (byte offset, dinv_j) built from scattered LDS reads. 64 lanes x
// 4B = one 256B quarter-row per iter, ~66 iters/wave. LDS 49KB ->
// 2 blocks/CU = 32 waves (full occupancy).
__global__ __launch_bounds__(1024) void spmm_kernel(
    const unsigned short* __restrict__ ell, const int* __restrict__ deg,
    const float* __restrict__ dinv, const unsigned short* __restrict__ Hs,
    const float* __restrict__ bias, float* __restrict__ out, int n, int D) {
  __shared__ float sdinv[8193];
  __shared__ uint2 ji[16][ELL_STRIDE];
  const int tid = threadIdx.x;
  const int wave = tid >> 6, lane = tid & 63;
  const int bid = blockIdx.x;
  const int qt = bid & 3;                     // quarter, XCD-pinned
  const int i = (bid >> 2) * 16 + wave;       // node (n divisible by 16)
  const unsigned rowbytes = (unsigned)(D * 2);

  for (int t = tid; t < n + 1; t += 1024) sdinv[t] = dinv[t];
  __syncthreads();

  {  // stage (byte offset, dinv[j]) — scattered LDS lookups, cheap
    const unsigned j0 = ell[(size_t)i * ELL_STRIDE + lane];
    const unsigned j1 = ell[(size_t)i * ELL_STRIDE + 64 + lane];
    ji[wave][lane] = make_uint2(j0 * rowbytes, __float_as_uint(sdinv[j0]));
    ji[wave][64 + lane] = make_uint2(j1 * rowbytes, __float_as_uint(sdinv[j1]));
  }
  const int d = deg[i];            // includes the self entry
  const float di = sdinv[i];
  const int kmax = (d + 7) & ~7;   // ELL pads (dinv 0, zero row) cover tail

  // this wave reads bytes [qt*256, qt*256+256) of each row: 4B per lane
  const char* __restrict__ hb = (const char*)Hs + qt * 256 + lane * 4;
  float a0 = 0.f, a1 = 0.f;

#pragma unroll 8
  for (int k = 0; k < kmax; ++k) {
    const uint2 e = ji[wave][k];  // uniform addr -> LDS broadcast
    const float dj = __uint_as_float(e.y);
    const unsigned hv = *(const unsigned*)(hb + e.x);
    a0 += dj * bflo(hv);
    a1 += dj * bfhi(hv);
  }

  const int col = qt * (D >> 2) + lane * 2;
  const float2 b = *(const float2*)(bias + col);
  f32x2 o;
  o.x = di * a0 + b.x;
  o.y = di * a1 + b.y;
  __builtin_nontemporal_store(o, (f32x2*)(out + (size_t)i * D + col));
}

extern "C" void kernel_launch(void* const* d_in, const int* in_sizes, int n_in,
                              void* d_out, int out_size, void* d_ws, size_t ws_size,
                              hipStream_t stream) {
  const float* x    = (const float*)d_in[0];
  const int*   ei   = (const int*)d_in[1];
  const float* W    = (const float*)d_in[2];
  const float* bias = (const float*)d_in[3];
  float* out = (float*)d_out;

  const int d_out_dim = in_sizes[3];             // 512
  const int d_in_dim  = in_sizes[2] / d_out_dim; // 512
  const int n_nodes   = in_sizes[0] / d_in_dim;  // 8192
  const int n_edges   = in_sizes[1] / 2;         // 262144
  const int words     = (n_nodes + 31) / 32;     // 256

  // workspace layout (bytes)
  char* ws = (char*)d_ws;
  size_t off = 0;
  unsigned* mask = (unsigned*)(ws + off); off += (size_t)n_nodes * words * 4;       // 8 MB
  int* deg       = (int*)(ws + off);      off += (size_t)n_nodes * 4;               // 32 KB
  float* dinv    = (float*)(ws + off);    off += (size_t)(n_nodes + 1) * 4;         // 32 KB + pad
  unsigned short* ell = (unsigned short*)(ws + off); off += (size_t)n_nodes * ELL_STRIDE * 2; // 2 MB
  unsigned short* xb  = (unsigned short*)(ws + off); off += (size_t)n_nodes * d_in_dim * 2;   // 8 MB
  unsigned short* Wt  = (unsigned short*)(ws + off); off += (size_t)d_in_dim * d_out_dim * 2; // 512 KB
  unsigned short* Hs  = (unsigned short*)(ws + off);
  off += (size_t)(n_nodes + 1) * d_out_dim * 2;  // 8 MB + pad row

  // 1) prep: memset mask | cast | transpose | pads
  const int mask_words_total = n_nodes * words;               // 2M words
  const int mset_blocks = (mask_words_total / 4 + 1023) / 1024;  // 512
  const int n4 = n_nodes * d_in_dim / 4;
  const int cast_blocks = (n4 + 255) / 256;                   // 4096
  const int tr_blocks = (d_in_dim / 32) * (d_out_dim / 32);   // 256
  prep_kernel<<<mset_blocks + cast_blocks + tr_blocks + 1, 256, 0, stream>>>(
      mask, mask_words_total, x, xb, n4, W, Wt, d_in_dim, d_out_dim,
      Hs, dinv, n_nodes, mset_blocks, cast_blocks, tr_blocks);

  // 2) front2: gemm (launches first, fills CUs) | edge atomics (hide under)
  const int nbx = d_out_dim / 128;                            // 4
  const int nbx_sh = 31 - __builtin_clz(nbx);                 // 2
  const int gemm_blocks = nbx * (n_nodes / 64);               // 512
  const int edge_blocks = (n_edges + 255) / 256;              // 1024
  front2_kernel<<<gemm_blocks + edge_blocks, 256, 0, stream>>>(
      xb, Wt, Hs, ei, mask, n_edges,
      n_nodes, d_out_dim, d_in_dim, words, gemm_blocks, nbx_sh);

  // 3) ell: LDS-buffered build + coalesced row store, deg + dinv
  ell_kernel<<<n_nodes / 4, 256, 0, stream>>>(mask, ell, deg, dinv,
                                              n_nodes, words);

  // 4) spmm: r9 core (quarter-D XCD-pinned, sdinv LDS table)
  const int spmm_blocks = 4 * (n_nodes / 16);                 // 2048
  spmm_kernel<<<spmm_blocks, 1024, 0, stream>>>(ell, deg, dinv, Hs, bias, out,
                                                n_nodes, d_out_dim);
}